// Round 1
// baseline (545.318 us; speedup 1.0000x reference)
//
#include <hip/hip_runtime.h>

// 3x3 PCF soft-shadow:
// vis[i] = (1/9) * sum_{ii,jj in [-1,1]} sigmoid((zbuf[b, clip(y+ii), clip(x+jj)] - (depth_z[i]-BIAS)) * 1000)

#define SHARPNESS 1000.0f
#define BIAS 0.008f

__global__ __launch_bounds__(256) void pcf_shadow_kernel(
    const float* __restrict__ zbuf,      // [N, S, S]
    const float* __restrict__ depth_z,   // [N, H, W, K] flat
    const int2*  __restrict__ xy,        // [N, H, W, K] pairs (x, y)
    const int*   __restrict__ image_size_p,
    float*       __restrict__ out,       // [N, H, W, K] flat
    int total,                           // N*H*W*K
    int zbuf_elems)                      // N*S*S
{
    const int i = blockIdx.x * blockDim.x + threadIdx.x;
    if (i >= total) return;

    const int S   = *image_size_p;       // uniform scalar load
    const int SS  = S * S;
    const int N   = zbuf_elems / SS;
    const int hwk = total / N;
    const int b   = i / hwk;

    const float a  = depth_z[i] - BIAS;
    const int2  p  = xy[i];
    const int   x  = p.x;
    const int   y  = p.y;

    const float* base = zbuf + (long long)b * (long long)SS;

    float vis = 0.0f;
#pragma unroll
    for (int ii = -1; ii <= 1; ++ii) {
        const int yi = min(max(y + ii, 0), S - 1);
        const float* row = base + (long long)yi * (long long)S;
#pragma unroll
        for (int jj = -1; jj <= 1; ++jj) {
            const int xi = min(max(x + jj, 0), S - 1);
            const float bb = row[xi];
            const float t  = (bb - a) * SHARPNESS;
            // sigmoid(t) = 1 / (1 + exp(-t)); saturates correctly at +-inf
            vis += 1.0f / (1.0f + __expf(-t));
        }
    }
    out[i] = vis * (1.0f / 9.0f);
}

extern "C" void kernel_launch(void* const* d_in, const int* in_sizes, int n_in,
                              void* d_out, int out_size, void* d_ws, size_t ws_size,
                              hipStream_t stream) {
    const float* zbuf     = (const float*)d_in[0];
    const float* depth_z  = (const float*)d_in[1];
    const int2*  xy       = (const int2*)d_in[2];
    const int*   img_size = (const int*)d_in[3];
    float*       out      = (float*)d_out;

    const int total      = in_sizes[1];  // N*H*W*K
    const int zbuf_elems = in_sizes[0];  // N*S*S

    const int block = 256;
    const int grid  = (total + block - 1) / block;
    pcf_shadow_kernel<<<grid, block, 0, stream>>>(zbuf, depth_z, xy, img_size,
                                                  out, total, zbuf_elems);
}